// Round 9
// baseline (1035.251 us; speedup 1.0000x reference)
//
#include <hip/hip_runtime.h>
#include <hip/hip_bf16.h>

#define DEVFN static __device__ __forceinline__

constexpr int NN = 16384;
constexpr int EE = 65536;
constexpr int GG = 512;
constexpr float AVG_LOG_F = 1.0227308671603782f; // (sum d*log d, d=1..4, hist 1,2,3,4)/10

typedef __attribute__((ext_vector_type(8))) short bfrag; // 8 bf16 = 4 VGPR
typedef __attribute__((ext_vector_type(4))) float f4;    // MFMA C/D

// fp32 -> bf16 (RNE) bit helpers
DEVFN unsigned short f2bf(float f) {
  unsigned int u = __float_as_uint(f);
  unsigned int r = (u + 0x7fffu + ((u >> 16) & 1u)) >> 16;
  return (unsigned short)r;
}
DEVFN float bf2f(unsigned short s) { return __uint_as_float(((unsigned int)s) << 16); }

// aux pointer bundle for fused A-staging modes
struct AuxP {
  const float* p0;
  const float* p1;
  const float* p2;
  const float* p3;
  const float* p4;
};

// ---------------------------------------------------------------------------
// Split-bf16 MFMA GEMM: C[M,Nc] = A[M,K] @ W[K,Nc](fp32, pre-split hi/lo)
// A-staging modes (ASRC):
//   1: bf16 ushort input, direct copy (2 MFMA)
//   3: PNA post-combine fused: A = Px + P_id + s*P_amp + invs*P_att + bpost
//   4: fp32 / rowcount (p0=cntf) -- global mean pool divide
//   5: pre-split hi/lo ushort arrays (Av=hi, p0=lo), pure copies, 3 MFMA
// GATHER: A row r comes from ridx[r] (CSR reorder).
// MF: epilogue computes m[slot] = (AB[nid[row]] + AB[nsrc[row]]+128) + (acc+bias)
//     (bit-identical to old aggregate input order ((A+B)+C))
// blockIdx.z batches via element strides bsA/bsW/bsC/bsBias (and bsM for MF).
// Block 256 = 4 waves; tile M=128, N=64, BK=32. M%128==0, K%32==0, col<Nc guarded.
// ---------------------------------------------------------------------------
template <int ASRC, bool BIAS, bool RELU, bool GATHER, bool MF>
__global__ __launch_bounds__(256) void mgemm(
    const void* __restrict__ Av, const unsigned short* __restrict__ WThi,
    const unsigned short* __restrict__ WTlo, const float* __restrict__ bias,
    float* __restrict__ C, const int* __restrict__ ridx, AuxP aux,
    const int* __restrict__ nid, const int* __restrict__ nsrc,
    const float* __restrict__ ABm, long long bsM,
    int Nc, int K, int lda, int ldc,
    long long bsA, long long bsW, long long bsC, int bsBias)
{
  constexpr bool SPLITA = (ASRC != 1);
  const int z = blockIdx.z;
  WThi += (long long)z * bsW;
  WTlo += (long long)z * bsW;
  C += (long long)z * bsC;
  if (BIAS) bias += (long long)z * bsBias;

  __shared__ __align__(16) unsigned short Ah[128][40];
  __shared__ __align__(16) unsigned short Al[SPLITA ? 128 : 1][40];
  __shared__ __align__(16) unsigned short Bh[64][40];
  __shared__ __align__(16) unsigned short Bl[64][40];

  const int tid = threadIdx.x;
  const long long bm = (long long)blockIdx.x * 128;
  const int bn = blockIdx.y * 64;
  const int w = tid >> 6;
  const int lane = tid & 63;
  const int quad = lane >> 4;
  const int c16 = lane & 15;

  const int arow = tid >> 1;      // 0..127
  const int sel = tid & 1;        // half of 32-wide k-chunk
  const int brow = tid >> 2;      // 0..63
  const int bk8 = (tid & 3) * 8;  // 0,8,16,24

  long long rowsrc = GATHER ? (long long)ridx[bm + arow] : (bm + arow);

  f4 acc[2][4];
#pragma unroll
  for (int mt = 0; mt < 2; ++mt)
#pragma unroll
    for (int nt = 0; nt < 4; ++nt) acc[mt][nt] = (f4){0.f, 0.f, 0.f, 0.f};

  const unsigned short* whp = WThi + (long long)(bn + brow) * K + bk8;
  const unsigned short* wlp = WTlo + (long long)(bn + brow) * K + bk8;

  for (int k0 = 0; k0 < K; k0 += 32) {
    const int ck0 = k0 + sel * 16;
    if (ASRC == 1) {
      const unsigned short* A = (const unsigned short*)Av + (long long)z * bsA;
      const unsigned short* ap = A + rowsrc * lda + ck0;
      *(uint4*)&Ah[arow][sel * 16] = *(const uint4*)(ap);
      *(uint4*)&Ah[arow][sel * 16 + 8] = *(const uint4*)(ap + 8);
    } else if (ASRC == 5) {
      const unsigned short* Ahp = (const unsigned short*)Av + (long long)z * bsA;
      const unsigned short* Alp = (const unsigned short*)aux.p0 + (long long)z * bsA;
      const unsigned short* aph = Ahp + rowsrc * lda + ck0;
      const unsigned short* apl = Alp + rowsrc * lda + ck0;
      *(uint4*)&Ah[arow][sel * 16] = *(const uint4*)(aph);
      *(uint4*)&Ah[arow][sel * 16 + 8] = *(const uint4*)(aph + 8);
      *(uint4*)&Al[arow][sel * 16] = *(const uint4*)(apl);
      *(uint4*)&Al[arow][sel * 16 + 8] = *(const uint4*)(apl + 8);
    } else {
      float va[16];
      if (ASRC == 3) {
        long long n = bm + arow;
        const float* Prow = aux.p0 + n * 384 + (ck0 >> 5) * 96 + (ck0 & 31);
        const float* pxp = aux.p1 + n * 128 + ck0;
        float sv = aux.p2[n], iv = aux.p3[n];
#pragma unroll
        for (int i = 0; i < 16; ++i)
          va[i] = pxp[i] + Prow[i] + sv * Prow[32 + i] + iv * Prow[64 + i] +
                  aux.p4[ck0 + i];
      } else {
        const float* A = (const float*)Av + (long long)z * bsA;
        const float* ap = A + rowsrc * lda + ck0;
        float4 v0 = *(const float4*)(ap);
        float4 v1 = *(const float4*)(ap + 4);
        float4 v2 = *(const float4*)(ap + 8);
        float4 v3 = *(const float4*)(ap + 12);
        va[0] = v0.x; va[1] = v0.y; va[2] = v0.z; va[3] = v0.w;
        va[4] = v1.x; va[5] = v1.y; va[6] = v1.z; va[7] = v1.w;
        va[8] = v2.x; va[9] = v2.y; va[10] = v2.z; va[11] = v2.w;
        va[12] = v3.x; va[13] = v3.y; va[14] = v3.z; va[15] = v3.w;
        if (ASRC == 4) {
          float dc = fmaxf(aux.p0[rowsrc], 1.f);
#pragma unroll
          for (int i = 0; i < 16; ++i) va[i] /= dc;
        }
      }
#pragma unroll
      for (int i = 0; i < 16; ++i) {
        unsigned short h = f2bf(va[i]);
        Ah[arow][sel * 16 + i] = h;
        Al[arow][sel * 16 + i] = f2bf(va[i] - bf2f(h));
      }
    }
    *(uint4*)&Bh[brow][bk8] = *(const uint4*)(whp + k0);
    *(uint4*)&Bl[brow][bk8] = *(const uint4*)(wlp + k0);
    __syncthreads();

    bfrag ah[2], al[2];
#pragma unroll
    for (int mt = 0; mt < 2; ++mt) {
      int r = w * 32 + mt * 16 + c16;
      ah[mt] = *(const bfrag*)&Ah[r][quad * 8];
      if (SPLITA) al[mt] = *(const bfrag*)&Al[r][quad * 8];
    }
#pragma unroll
    for (int nt = 0; nt < 4; ++nt) {
      int r = nt * 16 + c16;
      bfrag bh = *(const bfrag*)&Bh[r][quad * 8];
      bfrag bl = *(const bfrag*)&Bl[r][quad * 8];
#pragma unroll
      for (int mt = 0; mt < 2; ++mt) {
        acc[mt][nt] = __builtin_amdgcn_mfma_f32_16x16x32_bf16(ah[mt], bh, acc[mt][nt], 0, 0, 0);
        if (SPLITA)
          acc[mt][nt] = __builtin_amdgcn_mfma_f32_16x16x32_bf16(al[mt], bh, acc[mt][nt], 0, 0, 0);
        acc[mt][nt] = __builtin_amdgcn_mfma_f32_16x16x32_bf16(ah[mt], bl, acc[mt][nt], 0, 0, 0);
      }
    }
    __syncthreads();
  }

  // epilogue: C/D layout col=lane&15, row=quad*4+reg
  float bv[4];
#pragma unroll
  for (int nt = 0; nt < 4; ++nt) {
    int col = bn + nt * 16 + c16;
    bv[nt] = (BIAS && col < Nc) ? bias[col] : 0.f;
  }
  const float* ABz = MF ? (ABm + (long long)z * bsM) : nullptr;
#pragma unroll
  for (int mt = 0; mt < 2; ++mt) {
#pragma unroll
    for (int r = 0; r < 4; ++r) {
      long long row = bm + w * 32 + mt * 16 + quad * 4 + r;
      const float* Ar = nullptr;
      const float* Br = nullptr;
      if (MF) {
        Ar = ABz + (long long)nid[row] * 256;
        Br = ABz + (long long)nsrc[row] * 256 + 128;
      }
#pragma unroll
      for (int nt = 0; nt < 4; ++nt) {
        int col = bn + nt * 16 + c16;
        if (col >= Nc) continue;
        float v = acc[mt][nt][r] + bv[nt];
        if (MF) v = (Ar[col] + Br[col]) + v; // ((A+B)+C), matches old order
        if (RELU) v = fmaxf(v, 0.f);
        C[row * ldc + col] = v;
      }
    }
  }
}

// ---------------------------------------------------------------------------
// Encoders (write pre-split hi/lo)
// ---------------------------------------------------------------------------
__global__ void node_enc(const float* __restrict__ x, const float* __restrict__ Wa,
                         const float* __restrict__ ba,
                         unsigned short* __restrict__ hh, unsigned short* __restrict__ hl)
{
  int n = blockIdx.x, c = threadIdx.x; // 128
  float acc = ba[c];
#pragma unroll
  for (int k = 0; k < 11; ++k) acc += x[n * 11 + k] * Wa[k * 128 + c];
  float v = fmaxf(acc, 0.f);
  unsigned short h = f2bf(v);
  hh[(long long)n * 128 + c] = h;
  hl[(long long)n * 128 + c] = f2bf(v - bf2f(h));
}

__global__ void edge_enc(const float* __restrict__ eat, const float* __restrict__ We,
                         const float* __restrict__ be,
                         unsigned short* __restrict__ eh, unsigned short* __restrict__ el)
{
  int e = blockIdx.x, c = threadIdx.x; // 128
  float acc = be[c];
#pragma unroll
  for (int k = 0; k < 4; ++k) acc += eat[e * 4 + k] * We[k * 128 + c];
  float v = fmaxf(acc, 0.f);
  unsigned short h = f2bf(v);
  eh[(long long)e * 128 + c] = h;
  el[(long long)e * 128 + c] = f2bf(v - bf2f(h));
}

// ---------------------------------------------------------------------------
// CSR build: count -> scan (also inits cursor + s/invs) -> scatter
// ---------------------------------------------------------------------------
__global__ void count_deg(const int* __restrict__ dst, int* __restrict__ degi)
{
  int e = blockIdx.x * 256 + threadIdx.x;
  if (e < EE) atomicAdd(&degi[dst[e]], 1);
}

__global__ __launch_bounds__(1024) void scan_k(const int* __restrict__ degi,
                                               int* __restrict__ row_off,
                                               int* __restrict__ cursor,
                                               float* __restrict__ s_arr,
                                               float* __restrict__ invs)
{
  __shared__ int tsum[1024];
  int t = threadIdx.x;
  int local[16];
  int base = t * 16;
  int s = 0;
#pragma unroll
  for (int i = 0; i < 16; ++i) { local[i] = s; s += degi[base + i]; }
  tsum[t] = s;
  __syncthreads();
  for (int off = 1; off < 1024; off <<= 1) {
    int v = (t >= off) ? tsum[t - off] : 0;
    __syncthreads();
    tsum[t] += v;
    __syncthreads();
  }
  int prev = (t == 0) ? 0 : tsum[t - 1];
#pragma unroll
  for (int i = 0; i < 16; ++i) {
    int start = prev + local[i];
    row_off[base + i] = start;
    cursor[base + i] = start;
    int cnt = degi[base + i];
    float degc = fmaxf((float)cnt, 1.f);
    float sv = logf(degc + 1.f) / AVG_LOG_F;
    s_arr[base + i] = sv;
    invs[base + i] = 1.f / sv;
  }
  if (t == 1023) row_off[NN] = tsum[1023];
}

__global__ void scatter_k(const int* __restrict__ src, const int* __restrict__ dst,
                          int* __restrict__ cursor,
                          int* __restrict__ eidx, int* __restrict__ esrc,
                          int* __restrict__ nid)
{
  int e = blockIdx.x * 256 + threadIdx.x;
  if (e >= EE) return;
  int d = dst[e];
  int slot = atomicAdd(&cursor[d], 1);
  eidx[slot] = e;
  esrc[slot] = src[e];
  nid[slot] = d;
}

// ---------------------------------------------------------------------------
// Weight folds (fp32) + transpose-split packers (fp32 -> bf16 hi/lo, [N][K])
// ---------------------------------------------------------------------------
__global__ __launch_bounds__(512) void fold_w(const float* __restrict__ We_conv,
                                              const float* __restrict__ Wpre,
                                              float* __restrict__ Wfold)
{
  int k = blockIdx.x & 127, l = blockIdx.x >> 7;
  int t = threadIdx.x >> 7, f = threadIdx.x & 127;
  const float* wc = We_conv + (long long)(l * 128 + k) * 128;
  const float* wp = Wpre + ((long long)((l * 4 + t) * 384 + 256)) * 128 + f;
  float acc = 0.f;
  for (int j = 0; j < 128; ++j) acc += wc[j] * wp[(long long)j * 128];
  Wfold[((long long)(l * 128 + k)) * 512 + threadIdx.x] = acc;
}

__global__ __launch_bounds__(512) void fold_b(const float* __restrict__ be_conv,
                                              const float* __restrict__ Wpre,
                                              const float* __restrict__ bpre,
                                              float* __restrict__ bfold)
{
  int l = blockIdx.x;
  int t = threadIdx.x >> 7, f = threadIdx.x & 127;
  const float* bc = be_conv + l * 128;
  const float* wp = Wpre + ((long long)((l * 4 + t) * 384 + 256)) * 128 + f;
  float acc = bpre[(l * 4 + t) * 128 + f];
  for (int j = 0; j < 128; ++j) acc += bc[j] * wp[(long long)j * 128];
  bfold[l * 512 + threadIdx.x] = acc;
}

DEVFN void wsplit(float v, unsigned short* hi, unsigned short* lo, long long o)
{
  unsigned short h = f2bf(v);
  hi[o] = h;
  lo[o] = f2bf(v - bf2f(h));
}

// preABT[lt][n(256)][k(128)]
__global__ void tsplit_preAB(const float* __restrict__ Wpre,
                             unsigned short* __restrict__ hi, unsigned short* __restrict__ lo)
{
  int b = blockIdx.x; // 12*256
  int lt = b >> 8, n = b & 255, k = threadIdx.x; // 128
  int row = (n < 128) ? k : (128 + k);
  int f = n & 127;
  float v = Wpre[((long long)(lt * 384 + row)) * 128 + f];
  wsplit(v, hi, lo, ((long long)(lt * 256 + n)) * 128 + k);
}

// WfoldT[lt][n(128)][k(128)] from Wfold[l][k][t*128+n]
__global__ void tsplit_fold(const float* __restrict__ Wfold,
                            unsigned short* __restrict__ hi, unsigned short* __restrict__ lo)
{
  int b = blockIdx.x; // 12*128
  int lt = b >> 7, n = b & 127, k = threadIdx.x; // 128
  int l = lt >> 2, t = lt & 3;
  float v = Wfold[((long long)(l * 128 + k)) * 512 + t * 128 + n];
  wsplit(v, hi, lo, ((long long)(lt * 128 + n)) * 128 + k);
}

// post3T[lt][c(128, pad>=96 zero)][r(512)]
__global__ __launch_bounds__(512) void tsplit_post3(const float* __restrict__ Wpost,
                                                    unsigned short* __restrict__ hi,
                                                    unsigned short* __restrict__ lo)
{
  int b = blockIdx.x; // 12*128
  int lt = b >> 7, c = b & 127;
  int r = threadIdx.x; // 512
  float v = 0.f;
  if (c < 96)
    v = Wpost[((long long)(lt * 1664 + 128 + (c >> 5) * 512 + r)) * 32 + (c & 31)];
  wsplit(v, hi, lo, ((long long)(lt * 128 + c)) * 512 + r);
}

// WxT[l][c(128)][k(128)]
__global__ void tsplit_wx(const float* __restrict__ Wpost,
                          unsigned short* __restrict__ hi, unsigned short* __restrict__ lo)
{
  int b = blockIdx.x; // 3*128
  int l = b >> 7, c = b & 127, k = threadIdx.x;
  float v = Wpost[((long long)((l * 4 + (c >> 5)) * 1664 + k)) * 32 + (c & 31)];
  wsplit(v, hi, lo, ((long long)(l * 128 + c)) * 128 + k);
}

// WlinT[l][n][k]
__global__ void tsplit_lin(const float* __restrict__ Wlin,
                           unsigned short* __restrict__ hi, unsigned short* __restrict__ lo)
{
  int b = blockIdx.x; // 3*128
  int l = b >> 7, n = b & 127, k = threadIdx.x;
  float v = Wlin[((long long)(l * 128 + k)) * 128 + n];
  wsplit(v, hi, lo, ((long long)(l * 128 + n)) * 128 + k);
}

// W1T[n(64)][k(128)]
__global__ void tsplit_w1(const float* __restrict__ W1,
                          unsigned short* __restrict__ hi, unsigned short* __restrict__ lo)
{
  int n = blockIdx.x; // 64
  int k = threadIdx.x; // 128
  wsplit(W1[k * 64 + n], hi, lo, (long long)n * 128 + k);
}

// ---------------------------------------------------------------------------
// Streaming aggregation over precomputed m (CSR slot order), z = tower in pair.
// Output aggs: [N][512] bf16 (mean|min|max|std) per tower slab.
// ---------------------------------------------------------------------------
__global__ __launch_bounds__(128) void aggregate_m(
    const float* __restrict__ Mb, const int* __restrict__ row_off,
    unsigned short* __restrict__ aggs)
{
  int z = blockIdx.z;
  const float* M = Mb + (long long)z * EE * 128;
  unsigned short* ag = aggs + (long long)z * NN * 512;
  int n = blockIdx.x;
  int c = threadIdx.x; // 128
  int beg = row_off[n], end = row_off[n + 1];
  int cnt = end - beg;
  float degc = fmaxf((float)cnt, 1.0f);

  float sum = 0.f, sq = 0.f;
  float mn = INFINITY, mx = -INFINITY;
  for (int slot = beg; slot < end; ++slot) {
    float m = M[(long long)slot * 128 + c];
    sum += m;
    sq += m * m;
    mn = fminf(mn, m);
    mx = fmaxf(mx, m);
  }

  float inv = 1.0f / degc;
  float mean = sum * inv;
  float var = sq * inv - mean * mean;
  float stdv = sqrtf(fmaxf(var, 0.f) + 1e-5f);
  float mnv = (cnt > 0) ? mn : 0.f;
  float mxv = (cnt > 0) ? mx : 0.f;
  long long base = (long long)n * 512 + c;
  ag[base] = f2bf(mean);
  ag[base + 128] = f2bf(mnv);
  ag[base + 256] = f2bf(mxv);
  ag[base + 384] = f2bf(stdv);
}

// ---------------------------------------------------------------------------
// BatchNorm stats over N rows, 128 cols; apply+split
// ---------------------------------------------------------------------------
__global__ __launch_bounds__(256) void bn_partial(const float* __restrict__ y,
                                                  float* __restrict__ colsum,
                                                  float* __restrict__ colsq)
{
  int c = threadIdx.x & 127;
  int rh = threadIdx.x >> 7;
  int r0 = blockIdx.x * 128;
  float s = 0.f, q = 0.f;
  for (int r = r0 + rh; r < r0 + 128; r += 2) {
    float v = y[(long long)r * 128 + c];
    s += v;
    q += v * v;
  }
  __shared__ float ps[256], pq[256];
  ps[threadIdx.x] = s;
  pq[threadIdx.x] = q;
  __syncthreads();
  if (threadIdx.x < 128) {
    atomicAdd(&colsum[c], ps[c] + ps[c + 128]);
    atomicAdd(&colsq[c], pq[c] + pq[c + 128]);
  }
}

__global__ void bn_apply_split(const float* __restrict__ y, const float* __restrict__ colsum,
                               const float* __restrict__ colsq, const float* __restrict__ g,
                               const float* __restrict__ b,
                               unsigned short* __restrict__ hh, unsigned short* __restrict__ hl)
{
  int n = blockIdx.x, c = threadIdx.x;
  float mean = colsum[c] * (1.f / 16384.f);
  float var = colsq[c] * (1.f / 16384.f) - mean * mean;
  float v = fmaxf((y[(long long)n * 128 + c] - mean) * rsqrtf(var + 1e-5f) * g[c] + b[c], 0.f);
  unsigned short h = f2bf(v);
  hh[(long long)n * 128 + c] = h;
  hl[(long long)n * 128 + c] = f2bf(v - bf2f(h));
}

// ---------------------------------------------------------------------------
// Global mean pool (BN+ReLU fused) + head
// ---------------------------------------------------------------------------
__global__ void pool_add(const float* __restrict__ y, const float* __restrict__ colsum,
                         const float* __restrict__ colsq, const float* __restrict__ g,
                         const float* __restrict__ b, const int* __restrict__ batch,
                         float* __restrict__ pooled, float* __restrict__ cntf)
{
  int n = blockIdx.x, c = threadIdx.x;
  float mean = colsum[c] * (1.f / 16384.f);
  float var = colsq[c] * (1.f / 16384.f) - mean * mean;
  float v = fmaxf((y[(long long)n * 128 + c] - mean) * rsqrtf(var + 1e-5f) * g[c] + b[c], 0.f);
  int bb = batch[n];
  atomicAdd(&pooled[(long long)bb * 128 + c], v);
  if (c == 0) atomicAdd(&cntf[bb], 1.f);
}

__global__ __launch_bounds__(256) void zstats(const float* __restrict__ z,
                                              float* __restrict__ zm, float* __restrict__ zv)
{
  int j = blockIdx.x; // 64 cols
  float s = 0.f, q = 0.f;
  for (int g = threadIdx.x; g < GG; g += 256) {
    float v = z[g * 64 + j];
    s += v;
    q += v * v;
  }
  __shared__ float ps[256], pq[256];
  ps[threadIdx.x] = s;
  pq[threadIdx.x] = q;
  __syncthreads();
  for (int st = 128; st > 0; st >>= 1) {
    if (threadIdx.x < st) {
      ps[threadIdx.x] += ps[threadIdx.x + st];
      pq[threadIdx.x] += pq[threadIdx.x + st];
    }
    __syncthreads();
  }
  if (threadIdx.x == 0) {
    float m = ps[0] / (float)GG;
    zm[j] = m;
    zv[j] = pq[0] / (float)GG - m * m;
  }
}

__global__ void final_out(const float* __restrict__ z, const float* __restrict__ zm,
                          const float* __restrict__ zv, const float* __restrict__ hg,
                          const float* __restrict__ hb, const float* __restrict__ W2,
                          const float* __restrict__ b2, float* __restrict__ out)
{
  int g = blockIdx.x;
  int j = threadIdx.x; // 64 = one wave
  float v = (z[g * 64 + j] - zm[j]) * rsqrtf(zv[j] + 1e-5f) * hg[j] + hb[j];
  float t = v * W2[j];
#pragma unroll
  for (int off = 32; off > 0; off >>= 1) t += __shfl_down(t, off);
  if (j == 0) out[g] = t + b2[0];
}

// ---------------------------------------------------------------------------
extern "C" void kernel_launch(void* const* d_in, const int* in_sizes, int n_in,
                              void* d_out, int out_size, void* d_ws, size_t ws_size,
                              hipStream_t stream)
{
  (void)in_sizes; (void)n_in; (void)out_size;
  const float* x = (const float*)d_in[0];
  const float* eat = (const float*)d_in[1];
  const int* ei = (const int*)d_in[2];
  const int* batch = (const int*)d_in[3];
  const float* Wa = (const float*)d_in[4];
  const float* ba = (const float*)d_in[5];
  const float* We = (const float*)d_in[6];
  const float* be = (const float*)d_in[7];
  const float* We_conv = (const float*)d_in[8];
  const float* be_conv = (const float*)d_in[9];
  const float* Wpre = (const float*)d_in[10];
  const float* bpre = (const float*)d_in[11];
  const float* Wpost = (const float*)d_in[12];
  const float* bpost = (const float*)d_in[13];
  const float* Wlin = (const float*)d_in[14];
  const float* blin = (const float*)d_in[15];
  const float* bng = (const float*)d_in[16];
  const float* bnb = (const float*)d_in[17];
  const float* W1 = (const float*)d_in[18];
  const float* b1 = (const float*)d_in[19];
  const float* hg = (const float*)d_in[20];
  const float* hb = (const float*)d_in[21];
  const float* W2 = (const float*)d_in[22];
  const float* b2 = (const float*)d_in[23];
  float* out = (float*)d_out;

  const int* srcI = ei;
  const int* dstI = ei + EE;

  char* ws = (char*)d_ws;
  size_t off = 0;
  auto alloc = [&](size_t bytes) -> char* {
    char* p = ws + off;
    off += (bytes + 255) & ~(size_t)255;
    return p;
  };

  // ~262 MB total (ws = 256 MiB = 268.4 MB)
  float* hn = (float*)alloc((size_t)NN * 128 * 4);
  unsigned short* hsh = (unsigned short*)alloc((size_t)NN * 128 * 2);
  unsigned short* hsl = (unsigned short*)alloc((size_t)NN * 128 * 2);
  unsigned short* eah = (unsigned short*)alloc((size_t)EE * 128 * 2);
  unsigned short* eal = (unsigned short*)alloc((size_t)EE * 128 * 2);
  float* AB = (float*)alloc((size_t)4 * NN * 256 * 4);       // [T][N][256] fp32
  char* Mregion = alloc((size_t)2 * EE * 128 * 4);           // m pair; later P|Px
  float* Mb = (float*)Mregion;
  float* P = (float*)Mregion;                                 // [N][384]
  float* Px = (float*)(Mregion + (size_t)NN * 384 * 4);       // [N][128]
  unsigned short* aggt = (unsigned short*)alloc((size_t)4 * NN * 512 * 2); // bf16 [T][N][512]
  float* s_arr = (float*)alloc((size_t)NN * 4);
  float* invs = (float*)alloc((size_t)NN * 4);
  int* degi = (int*)alloc((size_t)NN * 4);
  int* cursor = (int*)alloc((size_t)NN * 4);
  int* row_off = (int*)alloc((size_t)(NN + 1) * 4);
  int* eidx = (int*)alloc((size_t)EE * 4);
  int* esrc = (int*)alloc((size_t)EE * 4);
  int* nid = (int*)alloc((size_t)EE * 4);
  float* WfoldF = (float*)alloc((size_t)3 * 128 * 512 * 4);
  float* bfold = (float*)alloc((size_t)3 * 512 * 4);
  unsigned short* preABT_h = (unsigned short*)alloc((size_t)12 * 256 * 128 * 2);
  unsigned short* preABT_l = (unsigned short*)alloc((size_t)12 * 256 * 128 * 2);
  unsigned short* foldT_h = (unsigned short*)alloc((size_t)12 * 128 * 128 * 2);
  unsigned short* foldT_l = (unsigned short*)alloc((size_t)12 * 128 * 128 * 2);
  unsigned short* post3T_h = (unsigned short*)alloc((size_t)12 * 128 * 512 * 2);
  unsigned short* post3T_l = (unsigned short*)alloc((size_t)12 * 128 * 512 * 2);
  unsigned short* wxT_h = (unsigned short*)alloc((size_t)3 * 128 * 128 * 2);
  unsigned short* wxT_l = (unsigned short*)alloc((size_t)3 * 128 * 128 * 2);
  unsigned short* linT_h = (unsigned short*)alloc((size_t)3 * 128 * 128 * 2);
  unsigned short* linT_l = (unsigned short*)alloc((size_t)3 * 128 * 128 * 2);
  unsigned short* w1T_h = (unsigned short*)alloc((size_t)64 * 128 * 2);
  unsigned short* w1T_l = (unsigned short*)alloc((size_t)64 * 128 * 2);
  float* colstats = (float*)alloc(512 * 4); // two ping-pong buffers of 256
  float* pooled = (float*)alloc((size_t)GG * 128 * 4);
  float* cntf = (float*)alloc((size_t)GG * 4);
  float* zbuf = (float*)alloc((size_t)GG * 64 * 4);
  float* zm = (float*)alloc(64 * 4);
  float* zv = (float*)alloc(64 * 4);

  if (off > ws_size) return; // bail rather than corrupt

  float* cs[2] = {colstats, colstats + 256};

  // ---- graph structure ----
  hipMemsetAsync(degi, 0, (size_t)NN * 4, stream);
  count_deg<<<EE / 256, 256, 0, stream>>>(dstI, degi);
  scan_k<<<1, 1024, 0, stream>>>(degi, row_off, cursor, s_arr, invs);
  scatter_k<<<EE / 256, 256, 0, stream>>>(srcI, dstI, cursor, eidx, esrc, nid);

  // ---- encoders + weight folds/packing ----
  node_enc<<<NN, 128, 0, stream>>>(x, Wa, ba, hsh, hsl);
  edge_enc<<<EE, 128, 0, stream>>>(eat, We, be, eah, eal);
  fold_w<<<384, 512, 0, stream>>>(We_conv, Wpre, WfoldF);
  fold_b<<<3, 512, 0, stream>>>(be_conv, Wpre, bpre, bfold);
  tsplit_preAB<<<12 * 256, 128, 0, stream>>>(Wpre, preABT_h, preABT_l);
  tsplit_fold<<<12 * 128, 128, 0, stream>>>(WfoldF, foldT_h, foldT_l);
  tsplit_post3<<<12 * 128, 512, 0, stream>>>(Wpost, post3T_h, post3T_l);
  tsplit_wx<<<3 * 128, 128, 0, stream>>>(Wpost, wxT_h, wxT_l);
  tsplit_lin<<<3 * 128, 128, 0, stream>>>(Wlin, linT_h, linT_l);
  tsplit_w1<<<64, 128, 0, stream>>>(W1, w1T_h, w1T_l);

  for (int l = 0; l < 3; ++l) {
    hipMemsetAsync(cs[l & 1], 0, 256 * 4, stream);
    if (l > 0) {
      bn_apply_split<<<NN, 128, 0, stream>>>(hn, cs[(l + 1) & 1], cs[(l + 1) & 1] + 128,
                                             bng + (l - 1) * 128, bnb + (l - 1) * 128,
                                             hsh, hsl);
    }
    // AB all towers: [N,128] @ [128,256] (z=4) -> fp32 [T][N][256]
    mgemm<5, false, false, false, false><<<dim3(NN / 128, 4, 4), 256, 0, stream>>>(
        hsh, preABT_h + (size_t)l * 4 * 256 * 128, preABT_l + (size_t)l * 4 * 256 * 128,
        nullptr, AB, nullptr, AuxP{(const float*)hsl, nullptr, nullptr, nullptr, nullptr},
        nullptr, nullptr, nullptr, 0,
        256, 128, 128, 256, 0, (long long)256 * 128, (long long)NN * 256, 0);
    for (int pair = 0; pair < 2; ++pair) {
      int lt0 = l * 4 + pair * 2;
      // m (pair of towers): ea-gather GEMM + fused (A[dst]+B[src]) add in epilogue
      mgemm<5, true, false, true, true><<<dim3(EE / 128, 2, 2), 256, 0, stream>>>(
          eah, foldT_h + (size_t)lt0 * 128 * 128, foldT_l + (size_t)lt0 * 128 * 128,
          bfold + l * 512 + pair * 256, Mb, eidx,
          AuxP{(const float*)eal, nullptr, nullptr, nullptr, nullptr},
          nid, esrc, AB + (size_t)(pair * 2) * NN * 256, (long long)NN * 256,
          128, 128, 128, 128, 0, (long long)128 * 128, (long long)EE * 128, 128);
      // streaming stats over m
      aggregate_m<<<dim3(NN, 1, 2), 128, 0, stream>>>(
          Mb, row_off, aggt + (size_t)(pair * 2) * NN * 512);
    }
    // P all towers: bf16 [N,512] @ [512,96] (z=4) -> P[:, z*96..]
    mgemm<1, false, false, false, false><<<dim3(NN / 128, 2, 4), 256, 0, stream>>>(
        aggt, post3T_h + (size_t)l * 4 * 128 * 512, post3T_l + (size_t)l * 4 * 128 * 512,
        nullptr, P, nullptr, AuxP{}, nullptr, nullptr, nullptr, 0,
        96, 512, 512, 384, (long long)NN * 512, (long long)128 * 512, 96, 0);
    // Px: [N,128] @ [128,128]
    mgemm<5, false, false, false, false><<<dim3(NN / 128, 2, 1), 256, 0, stream>>>(
        hsh, wxT_h + (size_t)l * 128 * 128, wxT_l + (size_t)l * 128 * 128,
        nullptr, Px, nullptr, AuxP{(const float*)hsl, nullptr, nullptr, nullptr, nullptr},
        nullptr, nullptr, nullptr, 0, 128, 128, 128, 128, 0, 0, 0, 0);
    // lin (post-combine fused in A-staging): [N,128] @ [128,128] + blin -> hn
    mgemm<3, true, false, false, false><<<dim3(NN / 128, 2, 1), 256, 0, stream>>>(
        nullptr, linT_h + (size_t)l * 128 * 128, linT_l + (size_t)l * 128 * 128,
        blin + l * 128, hn, nullptr,
        AuxP{P, Px, s_arr, invs, bpost + l * 128},
        nullptr, nullptr, nullptr, 0, 128, 128, 128, 128, 0, 0, 0, 0);
    bn_partial<<<128, 256, 0, stream>>>(hn, cs[l & 1], cs[l & 1] + 128);
  }

  // ---- pooling (BN+ReLU fused) + head ----
  hipMemsetAsync(pooled, 0, (size_t)GG * 128 * 4, stream);
  hipMemsetAsync(cntf, 0, (size_t)GG * 4, stream);
  pool_add<<<NN, 128, 0, stream>>>(hn, cs[0], cs[0] + 128,
                                   bng + 2 * 128, bnb + 2 * 128, batch, pooled, cntf);
  mgemm<4, true, true, false, false><<<dim3(GG / 128, 1, 1), 256, 0, stream>>>(
      pooled, w1T_h, w1T_l, b1, zbuf, nullptr,
      AuxP{cntf, nullptr, nullptr, nullptr, nullptr},
      nullptr, nullptr, nullptr, 0, 64, 128, 128, 64, 0, 0, 0, 0);
  zstats<<<64, 256, 0, stream>>>(zbuf, zm, zv);
  final_out<<<GG, 64, 0, stream>>>(zbuf, zm, zv, hg, hb, W2, b2, out);
}

// Round 10
// 917.475 us; speedup vs baseline: 1.1284x; 1.1284x over previous
//
#include <hip/hip_runtime.h>
#include <hip/hip_bf16.h>

#define DEVFN static __device__ __forceinline__

constexpr int NN = 16384;
constexpr int EE = 65536;
constexpr int GG = 512;
constexpr float AVG_LOG_F = 1.0227308671603782f; // (sum d*log d, d=1..4, hist 1,2,3,4)/10

typedef __attribute__((ext_vector_type(8))) short bfrag; // 8 bf16 = 4 VGPR
typedef __attribute__((ext_vector_type(4))) float f4;    // MFMA C/D

// fp32 -> bf16 (RNE) bit helpers
DEVFN unsigned short f2bf(float f) {
  unsigned int u = __float_as_uint(f);
  unsigned int r = (u + 0x7fffu + ((u >> 16) & 1u)) >> 16;
  return (unsigned short)r;
}
DEVFN float bf2f(unsigned short s) { return __uint_as_float(((unsigned int)s) << 16); }

// aux pointer bundle for fused A-staging modes
struct AuxP {
  const float* p0;
  const float* p1;
  const float* p2;
  const float* p3;
  const float* p4;
};

// ---------------------------------------------------------------------------
// Split-bf16 MFMA GEMM: C[M,Nc] = A[M,K] @ W[K,Nc](fp32, pre-split hi/lo)
// A-staging modes (ASRC):
//   0: plain fp32, split on the fly (3 MFMA ~= fp32 GEMM)
//   1: bf16 ushort input, direct copy (2 MFMA)
//   2: fp32 + BatchNorm+ReLU fused (p0=colsum,p1=colsq,p2=gamma,p3=beta)
//   3: PNA post-combine fused: A = Px + P_id + s*P_amp + invs*P_att + bpost
//   4: fp32 / rowcount (p0=cntf) -- global mean pool divide
//   5: pre-split hi/lo ushort arrays (Av=hi, p0=lo), pure copies, 3 MFMA
// blockIdx.z batches via element strides bsA/bsW/bsC/bsBias.
// Block 256 = 4 waves; tile M=128, N=64, BK=32. M%128==0, K%32==0, col<Nc guarded.
// ---------------------------------------------------------------------------
template <int ASRC, bool BIAS, bool RELU>
__global__ __launch_bounds__(256) void mgemm(
    const void* __restrict__ Av, const unsigned short* __restrict__ WThi,
    const unsigned short* __restrict__ WTlo, const float* __restrict__ bias,
    float* __restrict__ C, AuxP aux,
    int Nc, int K, int lda, int ldc,
    long long bsA, long long bsW, long long bsC, int bsBias)
{
  constexpr bool SPLITA = (ASRC != 1);
  const int z = blockIdx.z;
  WThi += (long long)z * bsW;
  WTlo += (long long)z * bsW;
  C += (long long)z * bsC;
  if (BIAS) bias += (long long)z * bsBias;

  __shared__ __align__(16) unsigned short Ah[128][40];
  __shared__ __align__(16) unsigned short Al[SPLITA ? 128 : 1][40];
  __shared__ __align__(16) unsigned short Bh[64][40];
  __shared__ __align__(16) unsigned short Bl[64][40];

  const int tid = threadIdx.x;
  const long long bm = (long long)blockIdx.x * 128;
  const int bn = blockIdx.y * 64;
  const int w = tid >> 6;
  const int lane = tid & 63;
  const int quad = lane >> 4;
  const int c16 = lane & 15;

  const int arow = tid >> 1;      // 0..127
  const int sel = tid & 1;        // half of 32-wide k-chunk
  const int brow = tid >> 2;      // 0..63
  const int bk8 = (tid & 3) * 8;  // 0,8,16,24

  const long long rowsrc = bm + arow;

  f4 acc[2][4];
#pragma unroll
  for (int mt = 0; mt < 2; ++mt)
#pragma unroll
    for (int nt = 0; nt < 4; ++nt) acc[mt][nt] = (f4){0.f, 0.f, 0.f, 0.f};

  const unsigned short* whp = WThi + (long long)(bn + brow) * K + bk8;
  const unsigned short* wlp = WTlo + (long long)(bn + brow) * K + bk8;

  for (int k0 = 0; k0 < K; k0 += 32) {
    const int ck0 = k0 + sel * 16;
    if (ASRC == 1) {
      const unsigned short* A = (const unsigned short*)Av + (long long)z * bsA;
      const unsigned short* ap = A + rowsrc * lda + ck0;
      *(uint4*)&Ah[arow][sel * 16] = *(const uint4*)(ap);
      *(uint4*)&Ah[arow][sel * 16 + 8] = *(const uint4*)(ap + 8);
    } else if (ASRC == 5) {
      const unsigned short* Ahp = (const unsigned short*)Av + (long long)z * bsA;
      const unsigned short* Alp = (const unsigned short*)aux.p0 + (long long)z * bsA;
      const unsigned short* aph = Ahp + rowsrc * lda + ck0;
      const unsigned short* apl = Alp + rowsrc * lda + ck0;
      *(uint4*)&Ah[arow][sel * 16] = *(const uint4*)(aph);
      *(uint4*)&Ah[arow][sel * 16 + 8] = *(const uint4*)(aph + 8);
      *(uint4*)&Al[arow][sel * 16] = *(const uint4*)(apl);
      *(uint4*)&Al[arow][sel * 16 + 8] = *(const uint4*)(apl + 8);
    } else {
      float va[16];
      if (ASRC == 3) {
        long long n = bm + arow;
        const float* Prow = aux.p0 + n * 384 + (ck0 >> 5) * 96 + (ck0 & 31);
        const float* pxp = aux.p1 + n * 128 + ck0;
        float sv = aux.p2[n], iv = aux.p3[n];
#pragma unroll
        for (int i = 0; i < 16; ++i)
          va[i] = pxp[i] + Prow[i] + sv * Prow[32 + i] + iv * Prow[64 + i] +
                  aux.p4[ck0 + i];
      } else {
        const float* A = (const float*)Av + (long long)z * bsA;
        const float* ap = A + rowsrc * lda + ck0;
        float4 v0 = *(const float4*)(ap);
        float4 v1 = *(const float4*)(ap + 4);
        float4 v2 = *(const float4*)(ap + 8);
        float4 v3 = *(const float4*)(ap + 12);
        va[0] = v0.x; va[1] = v0.y; va[2] = v0.z; va[3] = v0.w;
        va[4] = v1.x; va[5] = v1.y; va[6] = v1.z; va[7] = v1.w;
        va[8] = v2.x; va[9] = v2.y; va[10] = v2.z; va[11] = v2.w;
        va[12] = v3.x; va[13] = v3.y; va[14] = v3.z; va[15] = v3.w;
        if (ASRC == 2) {
#pragma unroll
          for (int i = 0; i < 16; ++i) {
            int c = ck0 + i;
            float mean = aux.p0[c] * (1.f / 16384.f);
            float var = aux.p1[c] * (1.f / 16384.f) - mean * mean;
            va[i] = fmaxf((va[i] - mean) * rsqrtf(var + 1e-5f) * aux.p2[c] + aux.p3[c], 0.f);
          }
        }
        if (ASRC == 4) {
          float dc = fmaxf(aux.p0[rowsrc], 1.f);
#pragma unroll
          for (int i = 0; i < 16; ++i) va[i] /= dc;
        }
      }
#pragma unroll
      for (int i = 0; i < 16; ++i) {
        unsigned short h = f2bf(va[i]);
        Ah[arow][sel * 16 + i] = h;
        Al[arow][sel * 16 + i] = f2bf(va[i] - bf2f(h));
      }
    }
    *(uint4*)&Bh[brow][bk8] = *(const uint4*)(whp + k0);
    *(uint4*)&Bl[brow][bk8] = *(const uint4*)(wlp + k0);
    __syncthreads();

    bfrag ah[2], al[2];
#pragma unroll
    for (int mt = 0; mt < 2; ++mt) {
      int r = w * 32 + mt * 16 + c16;
      ah[mt] = *(const bfrag*)&Ah[r][quad * 8];
      if (SPLITA) al[mt] = *(const bfrag*)&Al[r][quad * 8];
    }
#pragma unroll
    for (int nt = 0; nt < 4; ++nt) {
      int r = nt * 16 + c16;
      bfrag bh = *(const bfrag*)&Bh[r][quad * 8];
      bfrag bl = *(const bfrag*)&Bl[r][quad * 8];
#pragma unroll
      for (int mt = 0; mt < 2; ++mt) {
        acc[mt][nt] = __builtin_amdgcn_mfma_f32_16x16x32_bf16(ah[mt], bh, acc[mt][nt], 0, 0, 0);
        if (SPLITA)
          acc[mt][nt] = __builtin_amdgcn_mfma_f32_16x16x32_bf16(al[mt], bh, acc[mt][nt], 0, 0, 0);
        acc[mt][nt] = __builtin_amdgcn_mfma_f32_16x16x32_bf16(ah[mt], bl, acc[mt][nt], 0, 0, 0);
      }
    }
    __syncthreads();
  }

  // epilogue: C/D layout col=lane&15, row=quad*4+reg
#pragma unroll
  for (int nt = 0; nt < 4; ++nt) {
    int col = bn + nt * 16 + c16;
    if (col >= Nc) continue;
    float bv = BIAS ? bias[col] : 0.f;
#pragma unroll
    for (int mt = 0; mt < 2; ++mt) {
#pragma unroll
      for (int r = 0; r < 4; ++r) {
        long long row = bm + w * 32 + mt * 16 + quad * 4 + r;
        float v = acc[mt][nt][r] + bv;
        if (RELU) v = fmaxf(v, 0.f);
        C[row * ldc + col] = v;
      }
    }
  }
}

// ---------------------------------------------------------------------------
// Encoders
// ---------------------------------------------------------------------------
__global__ void node_enc(const float* __restrict__ x, const float* __restrict__ Wa,
                         const float* __restrict__ ba, float* __restrict__ h)
{
  int n = blockIdx.x, c = threadIdx.x; // 128
  float acc = ba[c];
#pragma unroll
  for (int k = 0; k < 11; ++k) acc += x[n * 11 + k] * Wa[k * 128 + c];
  h[(long long)n * 128 + c] = fmaxf(acc, 0.f);
}

// writes split hi/lo DIRECTLY in CSR slot order (slot_of from scatter_k)
__global__ void edge_enc(const float* __restrict__ eat, const float* __restrict__ We,
                         const float* __restrict__ be, const int* __restrict__ slot_of,
                         unsigned short* __restrict__ eh, unsigned short* __restrict__ el)
{
  int e = blockIdx.x, c = threadIdx.x; // 128
  float acc = be[c];
#pragma unroll
  for (int k = 0; k < 4; ++k) acc += eat[e * 4 + k] * We[k * 128 + c];
  float v = fmaxf(acc, 0.f);
  unsigned short h = f2bf(v);
  long long slot = slot_of[e];
  eh[slot * 128 + c] = h;
  el[slot * 128 + c] = f2bf(v - bf2f(h));
}

// ---------------------------------------------------------------------------
// CSR build: count -> scan (also inits cursor + s/invs) -> scatter
// ---------------------------------------------------------------------------
__global__ void count_deg(const int* __restrict__ dst, int* __restrict__ degi)
{
  int e = blockIdx.x * 256 + threadIdx.x;
  if (e < EE) atomicAdd(&degi[dst[e]], 1);
}

__global__ __launch_bounds__(1024) void scan_k(const int* __restrict__ degi,
                                               int* __restrict__ row_off,
                                               int* __restrict__ cursor,
                                               float* __restrict__ s_arr,
                                               float* __restrict__ invs)
{
  __shared__ int tsum[1024];
  int t = threadIdx.x;
  int local[16];
  int base = t * 16;
  int s = 0;
#pragma unroll
  for (int i = 0; i < 16; ++i) { local[i] = s; s += degi[base + i]; }
  tsum[t] = s;
  __syncthreads();
  for (int off = 1; off < 1024; off <<= 1) {
    int v = (t >= off) ? tsum[t - off] : 0;
    __syncthreads();
    tsum[t] += v;
    __syncthreads();
  }
  int prev = (t == 0) ? 0 : tsum[t - 1];
#pragma unroll
  for (int i = 0; i < 16; ++i) {
    int start = prev + local[i];
    row_off[base + i] = start;
    cursor[base + i] = start;
    int cnt = degi[base + i];
    float degc = fmaxf((float)cnt, 1.f);
    float sv = logf(degc + 1.f) / AVG_LOG_F;
    s_arr[base + i] = sv;
    invs[base + i] = 1.f / sv;
  }
  if (t == 1023) row_off[NN] = tsum[1023];
}

__global__ void scatter_k(const int* __restrict__ src, const int* __restrict__ dst,
                          int* __restrict__ cursor,
                          int* __restrict__ slot_of, int* __restrict__ esrc)
{
  int e = blockIdx.x * 256 + threadIdx.x;
  if (e >= EE) return;
  int d = dst[e];
  int slot = atomicAdd(&cursor[d], 1);
  slot_of[e] = slot;
  esrc[slot] = src[e];
}

// ---------------------------------------------------------------------------
// Weight folds (fp32) + transpose-split packers (fp32 -> bf16 hi/lo, [N][K])
// ---------------------------------------------------------------------------
__global__ __launch_bounds__(512) void fold_w(const float* __restrict__ We_conv,
                                              const float* __restrict__ Wpre,
                                              float* __restrict__ Wfold)
{
  int k = blockIdx.x & 127, l = blockIdx.x >> 7;
  int t = threadIdx.x >> 7, f = threadIdx.x & 127;
  const float* wc = We_conv + (long long)(l * 128 + k) * 128;
  const float* wp = Wpre + ((long long)((l * 4 + t) * 384 + 256)) * 128 + f;
  float acc = 0.f;
  for (int j = 0; j < 128; ++j) acc += wc[j] * wp[(long long)j * 128];
  Wfold[((long long)(l * 128 + k)) * 512 + threadIdx.x] = acc;
}

__global__ __launch_bounds__(512) void fold_b(const float* __restrict__ be_conv,
                                              const float* __restrict__ Wpre,
                                              const float* __restrict__ bpre,
                                              float* __restrict__ bfold)
{
  int l = blockIdx.x;
  int t = threadIdx.x >> 7, f = threadIdx.x & 127;
  const float* bc = be_conv + l * 128;
  const float* wp = Wpre + ((long long)((l * 4 + t) * 384 + 256)) * 128 + f;
  float acc = bpre[(l * 4 + t) * 128 + f];
  for (int j = 0; j < 128; ++j) acc += bc[j] * wp[(long long)j * 128];
  bfold[l * 512 + threadIdx.x] = acc;
}

DEVFN void wsplit(float v, unsigned short* hi, unsigned short* lo, long long o)
{
  unsigned short h = f2bf(v);
  hi[o] = h;
  lo[o] = f2bf(v - bf2f(h));
}

// preABT[lt][n(256)][k(128)]
__global__ void tsplit_preAB(const float* __restrict__ Wpre,
                             unsigned short* __restrict__ hi, unsigned short* __restrict__ lo)
{
  int b = blockIdx.x; // 12*256
  int lt = b >> 8, n = b & 255, k = threadIdx.x; // 128
  int row = (n < 128) ? k : (128 + k);
  int f = n & 127;
  float v = Wpre[((long long)(lt * 384 + row)) * 128 + f];
  wsplit(v, hi, lo, ((long long)(lt * 256 + n)) * 128 + k);
}

// WfoldT[lt][n(128)][k(128)] from Wfold[l][k][t*128+n]
__global__ void tsplit_fold(const float* __restrict__ Wfold,
                            unsigned short* __restrict__ hi, unsigned short* __restrict__ lo)
{
  int b = blockIdx.x; // 12*128
  int lt = b >> 7, n = b & 127, k = threadIdx.x; // 128
  int l = lt >> 2, t = lt & 3;
  float v = Wfold[((long long)(l * 128 + k)) * 512 + t * 128 + n];
  wsplit(v, hi, lo, ((long long)(lt * 128 + n)) * 128 + k);
}

// post3T[lt][c(128, pad>=96 zero)][r(512)]
__global__ __launch_bounds__(512) void tsplit_post3(const float* __restrict__ Wpost,
                                                    unsigned short* __restrict__ hi,
                                                    unsigned short* __restrict__ lo)
{
  int b = blockIdx.x; // 12*128
  int lt = b >> 7, c = b & 127;
  int r = threadIdx.x; // 512
  float v = 0.f;
  if (c < 96)
    v = Wpost[((long long)(lt * 1664 + 128 + (c >> 5) * 512 + r)) * 32 + (c & 31)];
  wsplit(v, hi, lo, ((long long)(lt * 128 + c)) * 512 + r);
}

// WxT[l][c(128)][k(128)]
__global__ void tsplit_wx(const float* __restrict__ Wpost,
                          unsigned short* __restrict__ hi, unsigned short* __restrict__ lo)
{
  int b = blockIdx.x; // 3*128
  int l = b >> 7, c = b & 127, k = threadIdx.x;
  float v = Wpost[((long long)((l * 4 + (c >> 5)) * 1664 + k)) * 32 + (c & 31)];
  wsplit(v, hi, lo, ((long long)(l * 128 + c)) * 128 + k);
}

// WlinT[l][n][k]
__global__ void tsplit_lin(const float* __restrict__ Wlin,
                           unsigned short* __restrict__ hi, unsigned short* __restrict__ lo)
{
  int b = blockIdx.x; // 3*128
  int l = b >> 7, n = b & 127, k = threadIdx.x;
  float v = Wlin[((long long)(l * 128 + k)) * 128 + n];
  wsplit(v, hi, lo, ((long long)(l * 128 + n)) * 128 + k);
}

// W1T[n(64)][k(128)]
__global__ void tsplit_w1(const float* __restrict__ W1,
                          unsigned short* __restrict__ hi, unsigned short* __restrict__ lo)
{
  int n = blockIdx.x; // 64
  int k = threadIdx.x; // 128
  wsplit(W1[k * 64 + n], hi, lo, (long long)n * 128 + k);
}

// ---------------------------------------------------------------------------
// Per-tower aggregation; z = tower within pair. AB slab fp32 [N][256];
// C (in CSR slot order) streaming from Mb. Output aggs bf16 [N][512].
// m = ((A[n] + B[src]) + C[slot]) -- same order as r5/r7/r8.
// ---------------------------------------------------------------------------
__global__ __launch_bounds__(128) void aggregate_ct(
    const float* __restrict__ ABb, const float* __restrict__ Mb,
    const int* __restrict__ row_off, const int* __restrict__ esrc,
    unsigned short* __restrict__ aggs, int pair)
{
  int z = blockIdx.z;
  const float* M = Mb + (long long)z * EE * 128;
  const float* ABs = ABb + (long long)(pair * 2 + z) * NN * 256;
  unsigned short* ag = aggs + (long long)(pair * 2 + z) * NN * 512;
  int n = blockIdx.x;
  int c = threadIdx.x; // 128
  int beg = row_off[n], end = row_off[n + 1];
  int cnt = end - beg;
  float degc = fmaxf((float)cnt, 1.0f);

  float sum = 0.f, sq = 0.f;
  float mn = INFINITY, mx = -INFINITY;
  float aval = ABs[(long long)n * 256 + c];

  for (int slot = beg; slot < end; ++slot) {
    int sidx = esrc[slot];
    float m = aval + ABs[(long long)sidx * 256 + 128 + c] +
              M[(long long)slot * 128 + c];
    sum += m;
    sq += m * m;
    mn = fminf(mn, m);
    mx = fmaxf(mx, m);
  }

  float inv = 1.0f / degc;
  float mean = sum * inv;
  float var = sq * inv - mean * mean;
  float stdv = sqrtf(fmaxf(var, 0.f) + 1e-5f);
  float mnv = (cnt > 0) ? mn : 0.f;
  float mxv = (cnt > 0) ? mx : 0.f;
  long long base = (long long)n * 512 + c;
  ag[base] = f2bf(mean);
  ag[base + 128] = f2bf(mnv);
  ag[base + 256] = f2bf(mxv);
  ag[base + 384] = f2bf(stdv);
}

// ---------------------------------------------------------------------------
// BatchNorm stats over N rows, 128 cols
// ---------------------------------------------------------------------------
__global__ __launch_bounds__(256) void bn_partial(const float* __restrict__ y,
                                                  float* __restrict__ colsum,
                                                  float* __restrict__ colsq)
{
  int c = threadIdx.x & 127;
  int rh = threadIdx.x >> 7;
  int r0 = blockIdx.x * 128;
  float s = 0.f, q = 0.f;
  for (int r = r0 + rh; r < r0 + 128; r += 2) {
    float v = y[(long long)r * 128 + c];
    s += v;
    q += v * v;
  }
  __shared__ float ps[256], pq[256];
  ps[threadIdx.x] = s;
  pq[threadIdx.x] = q;
  __syncthreads();
  if (threadIdx.x < 128) {
    atomicAdd(&colsum[c], ps[c] + ps[c + 128]);
    atomicAdd(&colsq[c], pq[c] + pq[c + 128]);
  }
}

// ---------------------------------------------------------------------------
// Global mean pool (BN+ReLU fused) + head
// ---------------------------------------------------------------------------
__global__ void pool_add(const float* __restrict__ y, const float* __restrict__ colsum,
                         const float* __restrict__ colsq, const float* __restrict__ g,
                         const float* __restrict__ b, const int* __restrict__ batch,
                         float* __restrict__ pooled, float* __restrict__ cntf)
{
  int n = blockIdx.x, c = threadIdx.x;
  float mean = colsum[c] * (1.f / 16384.f);
  float var = colsq[c] * (1.f / 16384.f) - mean * mean;
  float v = fmaxf((y[(long long)n * 128 + c] - mean) * rsqrtf(var + 1e-5f) * g[c] + b[c], 0.f);
  int bb = batch[n];
  atomicAdd(&pooled[(long long)bb * 128 + c], v);
  if (c == 0) atomicAdd(&cntf[bb], 1.f);
}

__global__ __launch_bounds__(256) void zstats(const float* __restrict__ z,
                                              float* __restrict__ zm, float* __restrict__ zv)
{
  int j = blockIdx.x; // 64 cols
  float s = 0.f, q = 0.f;
  for (int g = threadIdx.x; g < GG; g += 256) {
    float v = z[g * 64 + j];
    s += v;
    q += v * v;
  }
  __shared__ float ps[256], pq[256];
  ps[threadIdx.x] = s;
  pq[threadIdx.x] = q;
  __syncthreads();
  for (int st = 128; st > 0; st >>= 1) {
    if (threadIdx.x < st) {
      ps[threadIdx.x] += ps[threadIdx.x + st];
      pq[threadIdx.x] += pq[threadIdx.x + st];
    }
    __syncthreads();
  }
  if (threadIdx.x == 0) {
    float m = ps[0] / (float)GG;
    zm[j] = m;
    zv[j] = pq[0] / (float)GG - m * m;
  }
}

__global__ void final_out(const float* __restrict__ z, const float* __restrict__ zm,
                          const float* __restrict__ zv, const float* __restrict__ hg,
                          const float* __restrict__ hb, const float* __restrict__ W2,
                          const float* __restrict__ b2, float* __restrict__ out)
{
  int g = blockIdx.x;
  int j = threadIdx.x; // 64 = one wave
  float v = (z[g * 64 + j] - zm[j]) * rsqrtf(zv[j] + 1e-5f) * hg[j] + hb[j];
  float t = v * W2[j];
#pragma unroll
  for (int off = 32; off > 0; off >>= 1) t += __shfl_down(t, off);
  if (j == 0) out[g] = t + b2[0];
}

// ---------------------------------------------------------------------------
extern "C" void kernel_launch(void* const* d_in, const int* in_sizes, int n_in,
                              void* d_out, int out_size, void* d_ws, size_t ws_size,
                              hipStream_t stream)
{
  (void)in_sizes; (void)n_in; (void)out_size;
  const float* x = (const float*)d_in[0];
  const float* eat = (const float*)d_in[1];
  const int* ei = (const int*)d_in[2];
  const int* batch = (const int*)d_in[3];
  const float* Wa = (const float*)d_in[4];
  const float* ba = (const float*)d_in[5];
  const float* We = (const float*)d_in[6];
  const float* be = (const float*)d_in[7];
  const float* We_conv = (const float*)d_in[8];
  const float* be_conv = (const float*)d_in[9];
  const float* Wpre = (const float*)d_in[10];
  const float* bpre = (const float*)d_in[11];
  const float* Wpost = (const float*)d_in[12];
  const float* bpost = (const float*)d_in[13];
  const float* Wlin = (const float*)d_in[14];
  const float* blin = (const float*)d_in[15];
  const float* bng = (const float*)d_in[16];
  const float* bnb = (const float*)d_in[17];
  const float* W1 = (const float*)d_in[18];
  const float* b1 = (const float*)d_in[19];
  const float* hg = (const float*)d_in[20];
  const float* hb = (const float*)d_in[21];
  const float* W2 = (const float*)d_in[22];
  const float* b2 = (const float*)d_in[23];
  float* out = (float*)d_out;

  const int* srcI = ei;
  const int* dstI = ei + EE;

  char* ws = (char*)d_ws;
  size_t off = 0;
  auto alloc = [&](size_t bytes) -> char* {
    char* p = ws + off;
    off += (bytes + 255) & ~(size_t)255;
    return p;
  };

  // ~259 MB total (ws = 256 MiB = 268.4 MB)
  float* h0 = (float*)alloc((size_t)NN * 128 * 4);
  float* hn = (float*)alloc((size_t)NN * 128 * 4);
  unsigned short* eah = (unsigned short*)alloc((size_t)EE * 128 * 2); // CSR slot order
  unsigned short* eal = (unsigned short*)alloc((size_t)EE * 128 * 2);
  float* AB = (float*)alloc((size_t)4 * NN * 256 * 4);       // [T][N][256] fp32
  char* Mregion = alloc((size_t)2 * EE * 128 * 4);           // C pair; later P|Px
  float* Mb = (float*)Mregion;
  float* P = (float*)Mregion;                                 // [N][384]
  float* Px = (float*)(Mregion + (size_t)NN * 384 * 4);       // [N][128]
  unsigned short* aggt = (unsigned short*)alloc((size_t)4 * NN * 512 * 2); // bf16 [T][N][512]
  float* s_arr = (float*)alloc((size_t)NN * 4);
  float* invs = (float*)alloc((size_t)NN * 4);
  int* degi = (int*)alloc((size_t)NN * 4);
  int* cursor = (int*)alloc((size_t)NN * 4);
  int* row_off = (int*)alloc((size_t)(NN + 1) * 4);
  int* slot_of = (int*)alloc((size_t)EE * 4);
  int* esrc = (int*)alloc((size_t)EE * 4);
  float* WfoldF = (float*)alloc((size_t)3 * 128 * 512 * 4);
  float* bfold = (float*)alloc((size_t)3 * 512 * 4);
  unsigned short* preABT_h = (unsigned short*)alloc((size_t)12 * 256 * 128 * 2);
  unsigned short* preABT_l = (unsigned short*)alloc((size_t)12 * 256 * 128 * 2);
  unsigned short* foldT_h = (unsigned short*)alloc((size_t)12 * 128 * 128 * 2);
  unsigned short* foldT_l = (unsigned short*)alloc((size_t)12 * 128 * 128 * 2);
  unsigned short* post3T_h = (unsigned short*)alloc((size_t)12 * 128 * 512 * 2);
  unsigned short* post3T_l = (unsigned short*)alloc((size_t)12 * 128 * 512 * 2);
  unsigned short* wxT_h = (unsigned short*)alloc((size_t)3 * 128 * 128 * 2);
  unsigned short* wxT_l = (unsigned short*)alloc((size_t)3 * 128 * 128 * 2);
  unsigned short* linT_h = (unsigned short*)alloc((size_t)3 * 128 * 128 * 2);
  unsigned short* linT_l = (unsigned short*)alloc((size_t)3 * 128 * 128 * 2);
  unsigned short* w1T_h = (unsigned short*)alloc((size_t)64 * 128 * 2);
  unsigned short* w1T_l = (unsigned short*)alloc((size_t)64 * 128 * 2);
  float* colstats = (float*)alloc(512 * 4); // two ping-pong buffers of 256
  float* pooled = (float*)alloc((size_t)GG * 128 * 4);
  float* cntf = (float*)alloc((size_t)GG * 4);
  float* zbuf = (float*)alloc((size_t)GG * 64 * 4);
  float* zm = (float*)alloc(64 * 4);
  float* zv = (float*)alloc(64 * 4);

  if (off > ws_size) return; // bail rather than corrupt

  float* cs[2] = {colstats, colstats + 256};

  // ---- graph structure ----
  hipMemsetAsync(degi, 0, (size_t)NN * 4, stream);
  count_deg<<<EE / 256, 256, 0, stream>>>(dstI, degi);
  scan_k<<<1, 1024, 0, stream>>>(degi, row_off, cursor, s_arr, invs);
  scatter_k<<<EE / 256, 256, 0, stream>>>(srcI, dstI, cursor, slot_of, esrc);

  // ---- encoders + weight folds/packing ----
  node_enc<<<NN, 128, 0, stream>>>(x, Wa, ba, h0);
  edge_enc<<<EE, 128, 0, stream>>>(eat, We, be, slot_of, eah, eal); // after scatter_k
  fold_w<<<384, 512, 0, stream>>>(We_conv, Wpre, WfoldF);
  fold_b<<<3, 512, 0, stream>>>(be_conv, Wpre, bpre, bfold);
  tsplit_preAB<<<12 * 256, 128, 0, stream>>>(Wpre, preABT_h, preABT_l);
  tsplit_fold<<<12 * 128, 128, 0, stream>>>(WfoldF, foldT_h, foldT_l);
  tsplit_post3<<<12 * 128, 512, 0, stream>>>(Wpost, post3T_h, post3T_l);
  tsplit_wx<<<3 * 128, 128, 0, stream>>>(Wpost, wxT_h, wxT_l);
  tsplit_lin<<<3 * 128, 128, 0, stream>>>(Wlin, linT_h, linT_l);
  tsplit_w1<<<64, 128, 0, stream>>>(W1, w1T_h, w1T_l);

  for (int l = 0; l < 3; ++l) {
    hipMemsetAsync(cs[l & 1], 0, 256 * 4, stream);
    AuxP bnaux{cs[(l + 1) & 1], cs[(l + 1) & 1] + 128,
               bng + (l - 1) * 128, bnb + (l - 1) * 128, nullptr};
    const float* hc = (l == 0) ? h0 : hn;
    // AB all towers: [N,128] @ [128,256] (z=4) -> fp32 [T][N][256]
    if (l == 0)
      mgemm<0, false, false><<<dim3(NN / 128, 4, 4), 256, 0, stream>>>(
          hc, preABT_h + (size_t)l * 4 * 256 * 128, preABT_l + (size_t)l * 4 * 256 * 128,
          nullptr, AB, AuxP{}, 256, 128, 128, 256,
          0, (long long)256 * 128, (long long)NN * 256, 0);
    else
      mgemm<2, false, false><<<dim3(NN / 128, 4, 4), 256, 0, stream>>>(
          hc, preABT_h + (size_t)l * 4 * 256 * 128, preABT_l + (size_t)l * 4 * 256 * 128,
          nullptr, AB, bnaux, 256, 128, 128, 256,
          0, (long long)256 * 128, (long long)NN * 256, 0);
    for (int pair = 0; pair < 2; ++pair) {
      int lt0 = l * 4 + pair * 2;
      // C (pair of towers, streaming, CSR-ordered ea): [E,128]@[128,128]+bfold
      mgemm<5, true, false><<<dim3(EE / 128, 2, 2), 256, 0, stream>>>(
          eah, foldT_h + (size_t)lt0 * 128 * 128, foldT_l + (size_t)lt0 * 128 * 128,
          bfold + l * 512 + pair * 256, Mb,
          AuxP{(const float*)eal, nullptr, nullptr, nullptr, nullptr},
          128, 128, 128, 128, 0, (long long)128 * 128, (long long)EE * 128, 128);
      // stats over m = (A + B[src]) + C  (C streaming)
      aggregate_ct<<<dim3(NN, 1, 2), 128, 0, stream>>>(AB, Mb, row_off, esrc, aggt, pair);
    }
    // P all towers: bf16 [N,512] @ [512,96] (z=4) -> P[:, z*96..]
    mgemm<1, false, false><<<dim3(NN / 128, 2, 4), 256, 0, stream>>>(
        aggt, post3T_h + (size_t)l * 4 * 128 * 512, post3T_l + (size_t)l * 4 * 128 * 512,
        nullptr, P, AuxP{}, 96, 512, 512, 384,
        (long long)NN * 512, (long long)128 * 512, 96, 0);
    // Px: [N,128] @ [128,128]
    if (l == 0)
      mgemm<0, false, false><<<dim3(NN / 128, 2, 1), 256, 0, stream>>>(
          hc, wxT_h + (size_t)l * 128 * 128, wxT_l + (size_t)l * 128 * 128,
          nullptr, Px, AuxP{}, 128, 128, 128, 128, 0, 0, 0, 0);
    else
      mgemm<2, false, false><<<dim3(NN / 128, 2, 1), 256, 0, stream>>>(
          hc, wxT_h + (size_t)l * 128 * 128, wxT_l + (size_t)l * 128 * 128,
          nullptr, Px, bnaux, 128, 128, 128, 128, 0, 0, 0, 0);
    // lin (post-combine fused in A-staging): [N,128] @ [128,128] + blin -> hn
    mgemm<3, true, false><<<dim3(NN / 128, 2, 1), 256, 0, stream>>>(
        nullptr, linT_h + (size_t)l * 128 * 128, linT_l + (size_t)l * 128 * 128,
        blin + l * 128, hn, AuxP{P, Px, s_arr, invs, bpost + l * 128},
        128, 128, 128, 128, 0, 0, 0, 0);
    bn_partial<<<128, 256, 0, stream>>>(hn, cs[l & 1], cs[l & 1] + 128);
  }

  // ---- pooling (BN+ReLU fused) + head ----
  hipMemsetAsync(pooled, 0, (size_t)GG * 128 * 4, stream);
  hipMemsetAsync(cntf, 0, (size_t)GG * 4, stream);
  pool_add<<<NN, 128, 0, stream>>>(hn, cs[0], cs[0] + 128,
                                   bng + 2 * 128, bnb + 2 * 128, batch, pooled, cntf);
  mgemm<4, true, true><<<dim3(GG / 128, 1, 1), 256, 0, stream>>>(
      pooled, w1T_h, w1T_l, b1, zbuf,
      AuxP{cntf, nullptr, nullptr, nullptr, nullptr}, 64, 128, 128, 64, 0, 0, 0, 0);
  zstats<<<64, 256, 0, stream>>>(zbuf, zm, zv);
  final_out<<<GG, 64, 0, stream>>>(zbuf, zm, zv, hg, hb, W2, b2, out);
}